// Round 12
// baseline (469.476 us; speedup 1.0000x reference)
//
#include <hip/hip_runtime.h>
#include <hip/hip_fp16.h>

#define NB     4
#define H      512
#define W      512
#define ITERS  30
#define K      4             // max iterations fused per dispatch
#define TOLF   1e-05f
#define TOTAL  (NB*H*W*3)    // 3,145,728
#define BLK    512
#define NWAVES (BLK/64)      // 8
#define NBLKS  1024          // 4 images x 16x16 tiles of 32x32
#define HALO   8
#define EXT    48            // 32 + 2*HALO
#define LRS    48
#define LPS    (48*48)       // 2304
#define RRS    46            // rbt row stride (ext-1 coords, halfs)
#define RPS    (46*46)       // 2116
#define NQ1    552           // stage-1 quads: 46 rows x 12 quad-cols
#define NQ2    484           // stage-2 quads: 44 rows x 11 quad-cols
#define TBIG   1000000

typedef float v2f __attribute__((ext_vector_type(2)));

__device__ __forceinline__ v2f pkfma(v2f a, float w, v2f c) {
    return __builtin_elementwise_fma(a, (v2f){w, w}, c);
}

__device__ __forceinline__ int refl(int v, int n) {
    if (v < 0)  return -v;
    if (v >= n) return 2 * n - 2 - v;
    return v;
}

// One dispatch = up to K=4 fused RL iterations on a 32x32 tile, halo-8.
// R12: quad slots (2 adjacent pixel-pairs per thread, shared LDS reads,
// per-pair write guards) + packed v2f FMAs (v_pk_fma_f32). BLK=512 @
// launch_bounds(512,8): 4 blocks/CU x 8 waves = 32 waves/CU. rbt fp16 in
// ext-1 coords. Symmetric Gaussian => reflection commutes with conv
// (mirror band staged once). done-flag: optimistic run + deterministic
// partials scan; firing in the previous group => recompute from that
// group's intact source (period-3 buffer schedule).
__global__ __launch_bounds__(BLK, 8) void rl_group(
    const float* __restrict__ inputs,
    const float* __restrict__ gk,
    const float* __restrict__ gkf,
    const float* __restrict__ src,       // latent at group start
    const float* __restrict__ src_prev,  // latent at PREVIOUS group start
    float* __restrict__ dst,
    float* __restrict__ part,            // [30][1024] iteration partials
    int g)                               // 0..7 compute, 8 fixup
{
    __shared__ float  lat[3 * LPS];      // 27648 B
    __shared__ __half rbt[3 * RPS];      // 12696 B
    __shared__ float  wred[NWAVES];
    __shared__ int    s_tstar;

    const int tid  = threadIdx.x;
    const int lane = tid & 63;
    const int wid  = tid >> 6;
    const int b    = blockIdx.x;
    const int n    = b >> 8;
    const int rtile= b & 255;
    const int ty0  = (rtile >> 4) << 5;
    const int tx0  = (rtile & 15) << 5;
    const bool xe0 = (tx0 == 0), xe1 = (tx0 + 32 == W);
    const bool ye0 = (ty0 == 0), ye1 = (ty0 + 32 == H);
    const bool edge = xe0 | xe1 | ye0 | ye1;
    const size_t nbase = (size_t)n * (H * W * 3);
    const float* inp_n = inputs + nbase;

    const int base      = (4 * g < ITERS) ? 4 * g : ITERS;
    const int prev_base = (g > 0) ? 4 * (g - 1) : 0;

    // ---- deterministic scan: first firing iteration among prior groups ----
    int tstar = TBIG;
    if (g > 0) {
        const int tmax = base;
        if (tid == 0) s_tstar = TBIG;
        __syncthreads();
        for (int t = wid; t < tmax; t += NWAVES) {
            double a = 0.0;
            for (int q = lane; q < NBLKS; q += 64)
                a += (double)part[t * NBLKS + q];
            #pragma unroll
            for (int off = 32; off; off >>= 1) a += __shfl_down(a, off, 64);
            if (lane == 0) {
                const float mean = (float)(a / (double)TOTAL);
                if (fabsf(1.0f - mean) < TOLF) atomicMin(&s_tstar, t);
            }
        }
        __syncthreads();
        tstar = s_tstar;
    }

    // ---- mode decision (block-uniform, identical across all blocks) ----
    int m;
    const float* lsrc;
    bool wr_part;
    if (g == 0) {
        m = K; lsrc = src; wr_part = true;
    } else if (tstar >= base) {
        if (g == 8) return;
        m = (ITERS - base < K) ? (ITERS - base) : K;
        lsrc = src; wr_part = true;
    } else if (tstar >= prev_base) {
        m = tstar - prev_base + 1; lsrc = src_prev; wr_part = false;
    } else {
        if (g == 8) return;
        for (int p = tid; p < 1024; p += BLK) {
            const int i = p >> 5, j = p & 31;
            const size_t o = nbase + ((size_t)(ty0 + i) * W + (tx0 + j)) * 3;
            dst[o] = src[o]; dst[o + 1] = src[o + 1]; dst[o + 2] = src[o + 2];
        }
        return;
    }

    // ---- stage-1 quad metadata (2 slots): quad q: i=q/12+1, j=1+4*(q%12)
    // pairs (j,j+1) and (j+2,j+3); inputs offsets per pixel (reflected).
    int q1lat[2], q1rb[2], q1m0[2], q1m1[2];
    int q1o0[2], q1o1[2], q1o2[2], q1o3[2];
    #pragma unroll
    for (int up = 0; up < 2; ++up) {
        const int q = tid + up * BLK;
        q1m0[up] = -1; q1m1[up] = -1;
        if (q < NQ1) {
            const int i = q / 12 + 1;
            const int j = 4 * (q - (i - 1) * 12) + 1;
            q1lat[up] = i * LRS + j;
            q1rb[up]  = (i - 1) * RRS + (j - 1);
            const int vm = min(i - 1, 46 - i);
            q1m0[up] = min(vm, min(j - 1, 45 - j));
            q1m1[up] = (j + 2 <= 45) ? min(vm, min(j + 1, 43 - j)) : -1;
            const int ry = refl(ty0 - HALO + i, H);
            q1o0[up] = (ry * W + refl(tx0 - HALO + j,     W)) * 3;
            q1o1[up] = (ry * W + refl(tx0 - HALO + j + 1, W)) * 3;
            q1o2[up] = (ry * W + refl(tx0 - HALO + j + 2, W)) * 3;
            q1o3[up] = (ry * W + refl(tx0 - HALO + j + 3, W)) * 3;
        }
    }

    // ---- stage-2 quad metadata (1 slot): quad q: i=q/11+2, j=2+4*(q%11)
    int q2lat = 0, q2rb = 0, q2m0 = -1, q2m1 = -1, q2msk = 0;
    if (tid < NQ2) {
        const int i = tid / 11 + 2;
        const int j = 4 * (tid - (i - 2) * 11) + 2;
        q2lat = i * LRS + j;
        q2rb  = (i - 2) * RRS + (j - 2);
        const int vm = min(i - 2, 45 - i);
        q2m0 = min(vm, min(j - 2, 44 - j));
        q2m1 = min(vm, min(j, 42 - j));
        const bool iok = ((unsigned)(i - HALO) < 32u);
        q2msk = (iok && ((unsigned)(j     - HALO) < 32u) ? 1 : 0)
              | (iok && ((unsigned)(j + 1 - HALO) < 32u) ? 2 : 0)
              | (iok && ((unsigned)(j + 2 - HALO) < 32u) ? 4 : 0)
              | (iok && ((unsigned)(j + 3 - HALO) < 32u) ? 8 : 0);
    }

    // ---- stage 48x48 latent tile (in-image part) ----
    const float* s_n = lsrc + nbase;
    for (int p = tid; p < EXT * EXT; p += BLK) {
        const int i = p / EXT, j = p - i * EXT;
        const int gy = ty0 - HALO + i, gx = tx0 - HALO + j;
        if ((unsigned)gy < (unsigned)H && (unsigned)gx < (unsigned)W) {
            const float* sp = s_n + ((size_t)gy * W + gx) * 3;
            const int l = i * LRS + j;
            lat[l]           = sp[0];
            lat[LPS + l]     = sp[1];
            lat[2 * LPS + l] = sp[2];
        }
    }
    __syncthreads();

    // ---- mirror fixups (once): columns, then rows ----
    if (edge) {
        if (xe0) {
            for (int p = tid; p < 3 * EXT * HALO; p += BLK) {
                const int c = p / (EXT * HALO), rr = p - c * (EXT * HALO);
                const int i = rr / HALO, j = rr - i * HALO;
                lat[c * LPS + i * LRS + j] = lat[c * LPS + i * LRS + (16 - j)];
            }
        } else if (xe1) {
            for (int p = tid; p < 3 * EXT * HALO; p += BLK) {
                const int c = p / (EXT * HALO), rr = p - c * (EXT * HALO);
                const int i = rr / HALO, j2 = rr - i * HALO;
                lat[c * LPS + i * LRS + 40 + j2] = lat[c * LPS + i * LRS + (38 - j2)];
            }
        }
        __syncthreads();
        if (ye0) {
            for (int p = tid; p < 3 * HALO * EXT; p += BLK) {
                const int c = p / (HALO * EXT), rr = p - c * (HALO * EXT);
                const int i = rr / EXT, j = rr - i * EXT;
                lat[c * LPS + i * LRS + j] = lat[c * LPS + (16 - i) * LRS + j];
            }
        } else if (ye1) {
            for (int p = tid; p < 3 * HALO * EXT; p += BLK) {
                const int c = p / (HALO * EXT), rr = p - c * (HALO * EXT);
                const int i2 = rr / EXT, j = rr - i2 * EXT;
                lat[c * LPS + (40 + i2) * LRS + j] = lat[c * LPS + (38 - i2) * LRS + j];
            }
        }
        __syncthreads();
    }

    // ---- fused sub-iterations (2 barriers each) ----
    #pragma unroll
    for (int s = 0; s < K; ++s) {
        if (s >= m) break;
        const int s2 = 2 * s;

        // stage 1: rb = inp * rcp(conv(lat, k)). Quad: shared reads
        // f0=(j-1,j) f1=(j+1,j+2) f2=(j+3,j+4); per-pair write guards.
        #pragma unroll
        for (int up = 0; up < 2; ++up) {
            const bool a0ok = (s2 <= q1m0[up]);
            const bool a1ok = (s2 <= q1m1[up]);
            if (a0ok | a1ok) {
                const int lo = q1lat[up];
                const int ro = q1rb[up];
                #pragma unroll
                for (int c = 0; c < 3; ++c) {
                    const float* lc = &lat[c * LPS + lo];
                    v2f A0 = {0.f, 0.f}, A1 = {0.f, 0.f};
                    #pragma unroll
                    for (int dy = 0; dy < 3; ++dy) {
                        const float* rp = lc + (dy - 1) * LRS;
                        const float2 f0 = *(const float2*)(rp - 1);
                        const float2 f1 = *(const float2*)(rp + 1);
                        const float2 f2 = *(const float2*)(rp + 3);
                        const float w0 = gk[(dy * 3 + 0) * 3 + c];
                        const float w1 = gk[(dy * 3 + 1) * 3 + c];
                        const float w2 = gk[(dy * 3 + 2) * 3 + c];
                        A0 = pkfma((v2f){f0.x, f0.y}, w0, A0);
                        A0 = pkfma((v2f){f0.y, f1.x}, w1, A0);
                        A0 = pkfma((v2f){f1.x, f1.y}, w2, A0);
                        A1 = pkfma((v2f){f1.x, f1.y}, w0, A1);
                        A1 = pkfma((v2f){f1.y, f2.x}, w1, A1);
                        A1 = pkfma((v2f){f2.x, f2.y}, w2, A1);
                    }
                    if (a0ok) {
                        const float r0 = inp_n[q1o0[up] + c] * __builtin_amdgcn_rcpf(A0.x);
                        const float r1 = inp_n[q1o1[up] + c] * __builtin_amdgcn_rcpf(A0.y);
                        *(__half2*)&rbt[c * RPS + ro] = __floats2half2_rn(r0, r1);
                    }
                    if (a1ok) {
                        const float r2 = inp_n[q1o2[up] + c] * __builtin_amdgcn_rcpf(A1.x);
                        const float r3 = inp_n[q1o3[up] + c] * __builtin_amdgcn_rcpf(A1.y);
                        *(__half2*)&rbt[c * RPS + ro + 2] = __floats2half2_rn(r2, r3);
                    }
                }
            }
        }
        __syncthreads();

        // stage 2: e = conv(rb, kf); lat *= e; esum over interior.
        // Quad: shared reads g0=(j-2,j-1) g1=(j,j+1) g2=(j+2,j+3) in rb-local
        // cols; per-pair guards (exactness required for lat writes).
        float esum = 0.f;
        {
            const bool b0ok = (s2 <= q2m0);
            const bool b1ok = (s2 <= q2m1);
            if (b0ok | b1ok) {
                const int ro = q2rb;
                const int lo = q2lat;
                const int mk = q2msk;
                #pragma unroll
                for (int c = 0; c < 3; ++c) {
                    v2f E0 = {0.f, 0.f}, E1 = {0.f, 0.f};
                    #pragma unroll
                    for (int dy = 0; dy < 3; ++dy) {
                        const __half2* Rr = (const __half2*)
                            &rbt[c * RPS + ro + dy * RRS];
                        const float2 g0 = __half22float2(Rr[0]);
                        const float2 g1 = __half22float2(Rr[1]);
                        const float2 g2 = __half22float2(Rr[2]);
                        const float w0 = gkf[(dy * 3 + 0) * 3 + c];
                        const float w1 = gkf[(dy * 3 + 1) * 3 + c];
                        const float w2 = gkf[(dy * 3 + 2) * 3 + c];
                        E0 = pkfma((v2f){g0.x, g0.y}, w0, E0);
                        E0 = pkfma((v2f){g0.y, g1.x}, w1, E0);
                        E0 = pkfma((v2f){g1.x, g1.y}, w2, E0);
                        E1 = pkfma((v2f){g1.x, g1.y}, w0, E1);
                        E1 = pkfma((v2f){g1.y, g2.x}, w1, E1);
                        E1 = pkfma((v2f){g2.x, g2.y}, w2, E1);
                    }
                    if (b0ok) {
                        v2f* Lp = (v2f*)&lat[c * LPS + lo];
                        *Lp = *Lp * E0;
                        esum += (mk & 1) ? E0.x : 0.f;
                        esum += (mk & 2) ? E0.y : 0.f;
                    }
                    if (b1ok) {
                        v2f* Lp = (v2f*)&lat[c * LPS + lo + 2];
                        *Lp = *Lp * E1;
                        esum += (mk & 4) ? E1.x : 0.f;
                        esum += (mk & 8) ? E1.y : 0.f;
                    }
                }
            }
        }
        if (wr_part) {
            #pragma unroll
            for (int off = 32; off; off >>= 1) esum += __shfl_down(esum, off, 64);
            if (lane == 0) wred[wid] = esum;
        }
        __syncthreads();     // lat writes done AND wred ready
        if (wr_part && tid == 0) {
            float t = 0.f;
            #pragma unroll
            for (int w2 = 0; w2 < NWAVES; ++w2) t += wred[w2];
            part[(base + s) * NBLKS + b] = t;
        }
    }

    // ---- write interior [8,40)^2 to dst ----
    for (int p = tid; p < 1024; p += BLK) {
        const int i = p >> 5, j = p & 31;
        const int l = (i + HALO) * LRS + (j + HALO);
        float* op = dst + nbase + ((size_t)(ty0 + i) * W + (tx0 + j)) * 3;
        op[0] = lat[l];
        op[1] = lat[LPS + l];
        op[2] = lat[2 * LPS + l];
    }
}

extern "C" void kernel_launch(void* const* d_in, const int* in_sizes, int n_in,
                              void* d_out, int out_size, void* d_ws, size_t ws_size,
                              hipStream_t stream) {
    const float* inputs = (const float*)d_in[0];
    const float* gk     = (const float*)d_in[1];
    const float* gkf    = (const float*)d_in[2];
    float* out = (float*)d_out;

    // ws: [0 .. 128KB) iteration partials [30][1024] | buffer A | buffer B
    char* ws = (char*)d_ws;
    float* part = (float*)ws;
    float* A    = (float*)(ws + 131072);
    float* Bb   = (float*)(ws + 131072 + (size_t)TOTAL * sizeof(float));

    // period-3 schedule; X[g] = latent at start of group g. X[8] = out.
    const float* X[9] = { inputs, A, out, Bb, A, out, Bb, A, out };

    for (int g = 0; g < 9; ++g) {
        const float* s  = X[(g == 8) ? 7 : g];
        const float* sp = X[(g == 0) ? 0 : g - 1];
        float*       d  = (float*)((g == 8) ? X[8] : X[g + 1]);
        rl_group<<<NBLKS, BLK, 0, stream>>>(inputs, gk, gkf, s, sp, d, part, g);
    }
}

// Round 13
// 433.599 us; speedup vs baseline: 1.0827x; 1.0827x over previous
//
#include <hip/hip_runtime.h>
#include <hip/hip_fp16.h>

#define NB     4
#define H      512
#define W      512
#define ITERS  30
#define K      4             // max iterations fused per dispatch
#define TOLF   1e-05f
#define TOTAL  (NB*H*W*3)    // 3,145,728
#define BLK    512
#define NWAVES (BLK/64)      // 8
#define NBLKS  1024          // 4 images x 16x16 tiles of 32x32
#define HALO   8
#define EXT    48            // 32 + 2*HALO
#define LRS    48
#define LPS    (48*48)       // 2304
#define RRS    46            // rbt row stride (ext-1 coords, halfs)
#define RPS    (46*46)       // 2116
#define NP1    1058          // stage-1 pairs: 46 rows x 23 pair-cols
#define NP2    968           // stage-2 pairs: 44 rows x 22 pair-cols
#define S1S    3             // ceil(NP1/BLK)
#define S2S    2             // ceil(NP2/BLK)
#define TBIG   1000000

__device__ __forceinline__ int refl(int v, int n) {
    if (v < 0)  return -v;
    if (v >= n) return 2 * n - 2 - v;
    return v;
}

// One dispatch = up to K=4 fused RL iterations on a 32x32 tile, halo-8.
// R13 = R11 (the 419 us config: BLK=512 @ launch_bounds(512,8), 4 blocks/CU
// x 8 waves = 32 waves/CU, pair mapping with 8B lane stride) + the s-invariant
// `inputs` values register-cached before the K-loop (6 floats x S1S slots),
// removing global-load latency from every stage-1 critical path.
// rbt fp16 in ext-1 coords. Symmetric Gaussian => reflection commutes with
// conv (mirror band staged once). done-flag: optimistic run + deterministic
// partials scan; firing in the previous group => recompute from that group's
// intact source (period-3 buffer schedule).
__global__ __launch_bounds__(BLK, 8) void rl_group(
    const float* __restrict__ inputs,
    const float* __restrict__ gk,
    const float* __restrict__ gkf,
    const float* __restrict__ src,       // latent at group start
    const float* __restrict__ src_prev,  // latent at PREVIOUS group start
    float* __restrict__ dst,
    float* __restrict__ part,            // [30][1024] iteration partials
    int g)                               // 0..7 compute, 8 fixup
{
    __shared__ float  lat[3 * LPS];      // 27648 B
    __shared__ __half rbt[3 * RPS];      // 12696 B
    __shared__ float  wred[NWAVES];
    __shared__ int    s_tstar;

    const int tid  = threadIdx.x;
    const int lane = tid & 63;
    const int wid  = tid >> 6;
    const int b    = blockIdx.x;
    const int n    = b >> 8;
    const int rtile= b & 255;
    const int ty0  = (rtile >> 4) << 5;
    const int tx0  = (rtile & 15) << 5;
    const bool xe0 = (tx0 == 0), xe1 = (tx0 + 32 == W);
    const bool ye0 = (ty0 == 0), ye1 = (ty0 + 32 == H);
    const bool edge = xe0 | xe1 | ye0 | ye1;
    const size_t nbase = (size_t)n * (H * W * 3);
    const float* inp_n = inputs + nbase;

    const int base      = (4 * g < ITERS) ? 4 * g : ITERS;
    const int prev_base = (g > 0) ? 4 * (g - 1) : 0;

    // ---- deterministic scan: first firing iteration among prior groups ----
    int tstar = TBIG;
    if (g > 0) {
        const int tmax = base;
        if (tid == 0) s_tstar = TBIG;
        __syncthreads();
        for (int t = wid; t < tmax; t += NWAVES) {
            double a = 0.0;
            for (int q = lane; q < NBLKS; q += 64)
                a += (double)part[t * NBLKS + q];
            #pragma unroll
            for (int off = 32; off; off >>= 1) a += __shfl_down(a, off, 64);
            if (lane == 0) {
                const float mean = (float)(a / (double)TOTAL);
                if (fabsf(1.0f - mean) < TOLF) atomicMin(&s_tstar, t);
            }
        }
        __syncthreads();
        tstar = s_tstar;
    }

    // ---- mode decision (block-uniform, identical across all blocks) ----
    int m;
    const float* lsrc;
    bool wr_part;
    if (g == 0) {
        m = K; lsrc = src; wr_part = true;
    } else if (tstar >= base) {
        if (g == 8) return;
        m = (ITERS - base < K) ? (ITERS - base) : K;
        lsrc = src; wr_part = true;
    } else if (tstar >= prev_base) {
        m = tstar - prev_base + 1; lsrc = src_prev; wr_part = false;
    } else {
        if (g == 8) return;
        for (int p = tid; p < 1024; p += BLK) {
            const int i = p >> 5, j = p & 31;
            const size_t o = nbase + ((size_t)(ty0 + i) * W + (tx0 + j)) * 3;
            dst[o] = src[o]; dst[o + 1] = src[o + 1]; dst[o + 2] = src[o + 2];
        }
        return;
    }

    // ---- fixed stage-1 pair metadata + register-cached inputs ----
    // pair q: i = q/23 + 1 in [1,47), j = 2*(q%23) + 1 (odd)
    int   s1lat[S1S], s1rb[S1S], s1mrg[S1S];
    float ir0[S1S][3], ir1[S1S][3];      // s-invariant inputs values
    #pragma unroll
    for (int up = 0; up < S1S; ++up) {
        const int q = tid + up * BLK;
        s1mrg[up] = -1;
        if (q < NP1) {
            const int i = q / 23 + 1;
            const int j = 2 * (q - (i - 1) * 23) + 1;
            s1lat[up] = i * LRS + j;
            s1rb[up]  = (i - 1) * RRS + (j - 1);
            int mg = i - 1;
            mg = min(mg, 46 - i); mg = min(mg, j - 1); mg = min(mg, 45 - j);
            s1mrg[up] = mg;
            const int ry  = refl(ty0 - HALO + i, H);
            const int rx0 = refl(tx0 - HALO + j, W);
            const int rx1 = refl(tx0 - HALO + j + 1, W);
            const float* pa = inp_n + (ry * W + rx0) * 3;
            const float* pb = inp_n + (ry * W + rx1) * 3;
            #pragma unroll
            for (int c = 0; c < 3; ++c) { ir0[up][c] = pa[c]; ir1[up][c] = pb[c]; }
        }
    }

    // ---- fixed stage-2 pair metadata ----
    // pair q: i = q/22 + 2 in [2,46), j = 2*(q%22) + 2 (even)
    int s2lat[S2S], s2rb[S2S], s2mrg[S2S], s2msk[S2S];
    #pragma unroll
    for (int up = 0; up < S2S; ++up) {
        const int q = tid + up * BLK;
        s2mrg[up] = -1; s2msk[up] = 0;
        if (q < NP2) {
            const int i = q / 22 + 2;
            const int j = 2 * (q - (i - 2) * 22) + 2;
            s2lat[up] = i * LRS + j;
            s2rb[up]  = (i - 2) * RRS + (j - 2);
            int mg = i - 2;
            mg = min(mg, 45 - i); mg = min(mg, j - 2); mg = min(mg, 44 - j);
            s2mrg[up] = mg;
            const bool iok = ((unsigned)(i - HALO) < 32u);
            s2msk[up] = (iok && ((unsigned)(j - HALO) < 32u) ? 1 : 0)
                      | (iok && ((unsigned)(j + 1 - HALO) < 32u) ? 2 : 0);
        }
    }

    // ---- stage 48x48 latent tile (in-image part) ----
    const float* s_n = lsrc + nbase;
    for (int p = tid; p < EXT * EXT; p += BLK) {
        const int i = p / EXT, j = p - i * EXT;
        const int gy = ty0 - HALO + i, gx = tx0 - HALO + j;
        if ((unsigned)gy < (unsigned)H && (unsigned)gx < (unsigned)W) {
            const float* sp = s_n + ((size_t)gy * W + gx) * 3;
            const int l = i * LRS + j;
            lat[l]           = sp[0];
            lat[LPS + l]     = sp[1];
            lat[2 * LPS + l] = sp[2];
        }
    }
    __syncthreads();

    // ---- mirror fixups (once): columns, then rows ----
    if (edge) {
        if (xe0) {
            for (int p = tid; p < 3 * EXT * HALO; p += BLK) {
                const int c = p / (EXT * HALO), rr = p - c * (EXT * HALO);
                const int i = rr / HALO, j = rr - i * HALO;
                lat[c * LPS + i * LRS + j] = lat[c * LPS + i * LRS + (16 - j)];
            }
        } else if (xe1) {
            for (int p = tid; p < 3 * EXT * HALO; p += BLK) {
                const int c = p / (EXT * HALO), rr = p - c * (EXT * HALO);
                const int i = rr / HALO, j2 = rr - i * HALO;
                lat[c * LPS + i * LRS + 40 + j2] = lat[c * LPS + i * LRS + (38 - j2)];
            }
        }
        __syncthreads();
        if (ye0) {
            for (int p = tid; p < 3 * HALO * EXT; p += BLK) {
                const int c = p / (HALO * EXT), rr = p - c * (HALO * EXT);
                const int i = rr / EXT, j = rr - i * EXT;
                lat[c * LPS + i * LRS + j] = lat[c * LPS + (16 - i) * LRS + j];
            }
        } else if (ye1) {
            for (int p = tid; p < 3 * HALO * EXT; p += BLK) {
                const int c = p / (HALO * EXT), rr = p - c * (HALO * EXT);
                const int i2 = rr / EXT, j = rr - i2 * EXT;
                lat[c * LPS + (40 + i2) * LRS + j] = lat[c * LPS + (38 - i2) * LRS + j];
            }
        }
        __syncthreads();
    }

    // ---- fused sub-iterations (2 barriers each, offsets precomputed) ----
    #pragma unroll
    for (int s = 0; s < K; ++s) {
        if (s >= m) break;

        // stage 1: rb = inp * rcp(conv(lat, k)), fixed pairs, guard 2s<=mrg
        #pragma unroll
        for (int up = 0; up < S1S; ++up) {
            if (2 * s <= s1mrg[up]) {
                const int lo = s1lat[up];
                const int ro = s1rb[up];
                #pragma unroll
                for (int c = 0; c < 3; ++c) {
                    const float* lc = &lat[c * LPS + lo];
                    float a0 = 0.f, a1 = 0.f;
                    #pragma unroll
                    for (int dy = 0; dy < 3; ++dy) {
                        const float2 A  = *(const float2*)(lc + (dy - 1) * LRS - 1);
                        const float2 Bv = *(const float2*)(lc + (dy - 1) * LRS + 1);
                        const float w0 = gk[(dy * 3 + 0) * 3 + c];
                        const float w1 = gk[(dy * 3 + 1) * 3 + c];
                        const float w2 = gk[(dy * 3 + 2) * 3 + c];
                        a0 = fmaf(A.x, w0, fmaf(A.y, w1, fmaf(Bv.x, w2, a0)));
                        a1 = fmaf(A.y, w0, fmaf(Bv.x, w1, fmaf(Bv.y, w2, a1)));
                    }
                    const float r0 = ir0[up][c] * __builtin_amdgcn_rcpf(a0);
                    const float r1 = ir1[up][c] * __builtin_amdgcn_rcpf(a1);
                    *(__half2*)&rbt[c * RPS + ro] = __floats2half2_rn(r0, r1);
                }
            }
        }
        __syncthreads();

        // stage 2: e = conv(rb, kf); lat *= e; esum over interior.
        // rbt local col of ext x is x-1: output ext col j needs local
        // j-2..j+1 => q0 = (j-2,j-1), q1 = (j,j+1).
        float esum = 0.f;
        #pragma unroll
        for (int up = 0; up < S2S; ++up) {
            if (2 * s <= s2mrg[up]) {
                const int ro = s2rb[up];
                const int lo = s2lat[up];
                const int mk = s2msk[up];
                #pragma unroll
                for (int c = 0; c < 3; ++c) {
                    float e0 = 0.f, e1 = 0.f;
                    #pragma unroll
                    for (int dy = 0; dy < 3; ++dy) {
                        const __half2* Rr = (const __half2*)
                            &rbt[c * RPS + ro + dy * RRS];
                        const float2 q0 = __half22float2(Rr[0]);
                        const float2 q1 = __half22float2(Rr[1]);
                        const float w0 = gkf[(dy * 3 + 0) * 3 + c];
                        const float w1 = gkf[(dy * 3 + 1) * 3 + c];
                        const float w2 = gkf[(dy * 3 + 2) * 3 + c];
                        e0 = fmaf(q0.x, w0, fmaf(q0.y, w1, fmaf(q1.x, w2, e0)));
                        e1 = fmaf(q0.y, w0, fmaf(q1.x, w1, fmaf(q1.y, w2, e1)));
                    }
                    float2* Lp = (float2*)&lat[c * LPS + lo];
                    float2 lv = *Lp;
                    lv.x *= e0; lv.y *= e1;
                    *Lp = lv;
                    esum += (mk & 1) ? e0 : 0.f;
                    esum += (mk & 2) ? e1 : 0.f;
                }
            }
        }
        if (wr_part) {
            #pragma unroll
            for (int off = 32; off; off >>= 1) esum += __shfl_down(esum, off, 64);
            if (lane == 0) wred[wid] = esum;
        }
        __syncthreads();     // lat writes done AND wred ready
        if (wr_part && tid == 0) {
            float t = 0.f;
            #pragma unroll
            for (int w2 = 0; w2 < NWAVES; ++w2) t += wred[w2];
            part[(base + s) * NBLKS + b] = t;
        }
    }

    // ---- write interior [8,40)^2 to dst ----
    for (int p = tid; p < 1024; p += BLK) {
        const int i = p >> 5, j = p & 31;
        const int l = (i + HALO) * LRS + (j + HALO);
        float* op = dst + nbase + ((size_t)(ty0 + i) * W + (tx0 + j)) * 3;
        op[0] = lat[l];
        op[1] = lat[LPS + l];
        op[2] = lat[2 * LPS + l];
    }
}

extern "C" void kernel_launch(void* const* d_in, const int* in_sizes, int n_in,
                              void* d_out, int out_size, void* d_ws, size_t ws_size,
                              hipStream_t stream) {
    const float* inputs = (const float*)d_in[0];
    const float* gk     = (const float*)d_in[1];
    const float* gkf    = (const float*)d_in[2];
    float* out = (float*)d_out;

    // ws: [0 .. 128KB) iteration partials [30][1024] | buffer A | buffer B
    char* ws = (char*)d_ws;
    float* part = (float*)ws;
    float* A    = (float*)(ws + 131072);
    float* Bb   = (float*)(ws + 131072 + (size_t)TOTAL * sizeof(float));

    // period-3 schedule; X[g] = latent at start of group g. X[8] = out.
    const float* X[9] = { inputs, A, out, Bb, A, out, Bb, A, out };

    for (int g = 0; g < 9; ++g) {
        const float* s  = X[(g == 8) ? 7 : g];
        const float* sp = X[(g == 0) ? 0 : g - 1];
        float*       d  = (float*)((g == 8) ? X[8] : X[g + 1]);
        rl_group<<<NBLKS, BLK, 0, stream>>>(inputs, gk, gkf, s, sp, d, part, g);
    }
}

// Round 14
// 403.145 us; speedup vs baseline: 1.1645x; 1.0755x over previous
//
#include <hip/hip_runtime.h>
#include <hip/hip_fp16.h>

#define NB     4
#define H      512
#define W      512
#define ITERS  30
#define K      4             // max iterations fused per dispatch
#define TOLF   1e-05f
#define TOTAL  (NB*H*W*3)    // 3,145,728
#define BLK    512
#define NWAVES (BLK/64)      // 8
#define NBLKS  1024          // 4 images x 16x16 tiles of 32x32
#define HALO   8
#define EXT    48            // 32 + 2*HALO
#define LRS    48
#define LPS    (48*48)       // 2304
#define RRS    48            // rbt row stride (halfs) — 48 for aligned b64 writes
#define RPS    (46*48)       // 2208 (46 rows)
#define NQ1    552           // stage-1 quads: 46 rows x 12 quad-cols (4 px each)
#define NP2    968           // stage-2 pairs: 44 rows x 22 pair-cols
#define S2S    2             // ceil(NP2/BLK)
#define TBIG   1000000

__device__ __forceinline__ int refl(int v, int n) {
    if (v < 0)  return -v;
    if (v >= n) return 2 * n - 2 - v;
    return v;
}

// One dispatch = up to K=4 fused RL iterations on a 32x32 tile, halo-8.
// R14 = R11 (419 us: BLK=512 @ (512,8), 4 blocks/CU, 32 waves/CU) with
// stage-1 remapped to span-4 quads: one thread = 4 consecutive px x 3 ch.
// Quad origin j==1 mod 4 => window j-1..j+4 = one aligned float4 (b128) +
// one aligned float2 per row: 2x fewer stage-1 LDS read/write instructions,
// dense conflict-free pattern. Stage-1 over-compute is safe (garbage rb
// outside region s is never read); rim b64 writes land in junk cols 46/47
// of the 48-wide rbt rows. Stage-2 exact-guarded pair mapping: verbatim R11.
__global__ __launch_bounds__(BLK, 8) void rl_group(
    const float* __restrict__ inputs,
    const float* __restrict__ gk,
    const float* __restrict__ gkf,
    const float* __restrict__ src,       // latent at group start
    const float* __restrict__ src_prev,  // latent at PREVIOUS group start
    float* __restrict__ dst,
    float* __restrict__ part,            // [30][1024] iteration partials
    int g)                               // 0..7 compute, 8 fixup
{
    __shared__ float  lat[3 * LPS];      // 27648 B
    __shared__ __half rbt[3 * RPS];      // 13248 B
    __shared__ float  wred[NWAVES];      // 32 B
    __shared__ int    s_tstar;           // 4 B   (total 40932 <= 40960)

    const int tid  = threadIdx.x;
    const int lane = tid & 63;
    const int wid  = tid >> 6;
    const int b    = blockIdx.x;
    const int n    = b >> 8;
    const int rtile= b & 255;
    const int ty0  = (rtile >> 4) << 5;
    const int tx0  = (rtile & 15) << 5;
    const bool xe0 = (tx0 == 0), xe1 = (tx0 + 32 == W);
    const bool ye0 = (ty0 == 0), ye1 = (ty0 + 32 == H);
    const bool edge = xe0 | xe1 | ye0 | ye1;
    const size_t nbase = (size_t)n * (H * W * 3);
    const float* inp_n = inputs + nbase;

    const int base      = (4 * g < ITERS) ? 4 * g : ITERS;
    const int prev_base = (g > 0) ? 4 * (g - 1) : 0;

    // ---- deterministic scan: first firing iteration among prior groups ----
    int tstar = TBIG;
    if (g > 0) {
        const int tmax = base;
        if (tid == 0) s_tstar = TBIG;
        __syncthreads();
        for (int t = wid; t < tmax; t += NWAVES) {
            double a = 0.0;
            for (int q = lane; q < NBLKS; q += 64)
                a += (double)part[t * NBLKS + q];
            #pragma unroll
            for (int off = 32; off; off >>= 1) a += __shfl_down(a, off, 64);
            if (lane == 0) {
                const float mean = (float)(a / (double)TOTAL);
                if (fabsf(1.0f - mean) < TOLF) atomicMin(&s_tstar, t);
            }
        }
        __syncthreads();
        tstar = s_tstar;
    }

    // ---- mode decision (block-uniform, identical across all blocks) ----
    int m;
    const float* lsrc;
    bool wr_part;
    if (g == 0) {
        m = K; lsrc = src; wr_part = true;
    } else if (tstar >= base) {
        if (g == 8) return;
        m = (ITERS - base < K) ? (ITERS - base) : K;
        lsrc = src; wr_part = true;
    } else if (tstar >= prev_base) {
        m = tstar - prev_base + 1; lsrc = src_prev; wr_part = false;
    } else {
        if (g == 8) return;
        for (int p = tid; p < 1024; p += BLK) {
            const int i = p >> 5, j = p & 31;
            const size_t o = nbase + ((size_t)(ty0 + i) * W + (tx0 + j)) * 3;
            dst[o] = src[o]; dst[o + 1] = src[o + 1]; dst[o + 2] = src[o + 2];
        }
        return;
    }

    // ---- stage-1 quad metadata (2 slots) ----
    // quad q: i = q/12 + 1 in [1,47), j = 4*(q%12) + 1 (== 1 mod 4)
    // Active iff ANY of the 4 px is in region s (over-compute is safe).
    int q1lat[2], q1rb[2], q1mrg[2];
    int q1o0[2], q1o1[2], q1o2[2], q1o3[2];
    #pragma unroll
    for (int up = 0; up < 2; ++up) {
        const int q = tid + up * BLK;
        q1mrg[up] = -1;
        if (q < NQ1) {
            const int i = q / 12 + 1;
            const int j = 4 * (q - (i - 1) * 12) + 1;
            q1lat[up] = i * LRS + j;
            q1rb[up]  = (i - 1) * RRS + (j - 1);
            const int vm = min(i - 1, 46 - i);
            int cm = min(j - 1, 46 - j);
            cm = max(cm, min(j,     45 - j));
            cm = max(cm, min(j + 1, 44 - j));
            cm = max(cm, min(j + 2, 43 - j));
            q1mrg[up] = min(vm, cm);
            const int ry = refl(ty0 - HALO + i, H);
            q1o0[up] = (ry * W + refl(tx0 - HALO + j,     W)) * 3;
            q1o1[up] = (ry * W + refl(tx0 - HALO + j + 1, W)) * 3;
            q1o2[up] = (ry * W + refl(tx0 - HALO + j + 2, W)) * 3;
            q1o3[up] = (ry * W + refl(tx0 - HALO + j + 3, W)) * 3;
        }
    }

    // ---- fixed stage-2 pair metadata (verbatim R11, RRS=48) ----
    // pair q: i = q/22 + 2 in [2,46), j = 2*(q%22) + 2 (even)
    int s2lat[S2S], s2rb[S2S], s2mrg[S2S], s2msk[S2S];
    #pragma unroll
    for (int up = 0; up < S2S; ++up) {
        const int q = tid + up * BLK;
        s2mrg[up] = -1; s2msk[up] = 0;
        if (q < NP2) {
            const int i = q / 22 + 2;
            const int j = 2 * (q - (i - 2) * 22) + 2;
            s2lat[up] = i * LRS + j;
            s2rb[up]  = (i - 2) * RRS + (j - 2);
            int mg = i - 2;
            mg = min(mg, 45 - i); mg = min(mg, j - 2); mg = min(mg, 44 - j);
            s2mrg[up] = mg;
            const bool iok = ((unsigned)(i - HALO) < 32u);
            s2msk[up] = (iok && ((unsigned)(j - HALO) < 32u) ? 1 : 0)
                      | (iok && ((unsigned)(j + 1 - HALO) < 32u) ? 2 : 0);
        }
    }

    // ---- stage 48x48 latent tile (in-image part) ----
    const float* s_n = lsrc + nbase;
    for (int p = tid; p < EXT * EXT; p += BLK) {
        const int i = p / EXT, j = p - i * EXT;
        const int gy = ty0 - HALO + i, gx = tx0 - HALO + j;
        if ((unsigned)gy < (unsigned)H && (unsigned)gx < (unsigned)W) {
            const float* sp = s_n + ((size_t)gy * W + gx) * 3;
            const int l = i * LRS + j;
            lat[l]           = sp[0];
            lat[LPS + l]     = sp[1];
            lat[2 * LPS + l] = sp[2];
        }
    }
    __syncthreads();

    // ---- mirror fixups (once): columns, then rows ----
    if (edge) {
        if (xe0) {
            for (int p = tid; p < 3 * EXT * HALO; p += BLK) {
                const int c = p / (EXT * HALO), rr = p - c * (EXT * HALO);
                const int i = rr / HALO, j = rr - i * HALO;
                lat[c * LPS + i * LRS + j] = lat[c * LPS + i * LRS + (16 - j)];
            }
        } else if (xe1) {
            for (int p = tid; p < 3 * EXT * HALO; p += BLK) {
                const int c = p / (EXT * HALO), rr = p - c * (EXT * HALO);
                const int i = rr / HALO, j2 = rr - i * HALO;
                lat[c * LPS + i * LRS + 40 + j2] = lat[c * LPS + i * LRS + (38 - j2)];
            }
        }
        __syncthreads();
        if (ye0) {
            for (int p = tid; p < 3 * HALO * EXT; p += BLK) {
                const int c = p / (HALO * EXT), rr = p - c * (HALO * EXT);
                const int i = rr / EXT, j = rr - i * EXT;
                lat[c * LPS + i * LRS + j] = lat[c * LPS + (16 - i) * LRS + j];
            }
        } else if (ye1) {
            for (int p = tid; p < 3 * HALO * EXT; p += BLK) {
                const int c = p / (HALO * EXT), rr = p - c * (HALO * EXT);
                const int i2 = rr / EXT, j = rr - i2 * EXT;
                lat[c * LPS + (40 + i2) * LRS + j] = lat[c * LPS + (38 - i2) * LRS + j];
            }
        }
        __syncthreads();
    }

    // ---- fused sub-iterations (2 barriers each) ----
    #pragma unroll
    for (int s = 0; s < K; ++s) {
        if (s >= m) break;

        // stage 1: rb = inp * rcp(conv(lat, k)) — span-4 quads.
        // Row window j-1..j+4 = float4 (16B aligned) + float2 (8B aligned).
        #pragma unroll
        for (int up = 0; up < 2; ++up) {
            if (2 * s <= q1mrg[up]) {
                const int lo = q1lat[up];
                const int ro = q1rb[up];
                #pragma unroll
                for (int c = 0; c < 3; ++c) {
                    const float* lc = &lat[c * LPS + lo];
                    float a0 = 0.f, a1 = 0.f, a2 = 0.f, a3 = 0.f;
                    #pragma unroll
                    for (int dy = 0; dy < 3; ++dy) {
                        const float* rp = lc + (dy - 1) * LRS;
                        const float4 F = *(const float4*)(rp - 1);   // j-1..j+2
                        const float2 G = *(const float2*)(rp + 3);   // j+3,j+4
                        const float w0 = gk[(dy * 3 + 0) * 3 + c];
                        const float w1 = gk[(dy * 3 + 1) * 3 + c];
                        const float w2 = gk[(dy * 3 + 2) * 3 + c];
                        a0 = fmaf(F.x, w0, fmaf(F.y, w1, fmaf(F.z, w2, a0)));
                        a1 = fmaf(F.y, w0, fmaf(F.z, w1, fmaf(F.w, w2, a1)));
                        a2 = fmaf(F.z, w0, fmaf(F.w, w1, fmaf(G.x, w2, a2)));
                        a3 = fmaf(F.w, w0, fmaf(G.x, w1, fmaf(G.y, w2, a3)));
                    }
                    const float r0 = inp_n[q1o0[up] + c] * __builtin_amdgcn_rcpf(a0);
                    const float r1 = inp_n[q1o1[up] + c] * __builtin_amdgcn_rcpf(a1);
                    const float r2 = inp_n[q1o2[up] + c] * __builtin_amdgcn_rcpf(a2);
                    const float r3 = inp_n[q1o3[up] + c] * __builtin_amdgcn_rcpf(a3);
                    *(__half2*)&rbt[c * RPS + ro]     = __floats2half2_rn(r0, r1);
                    *(__half2*)&rbt[c * RPS + ro + 2] = __floats2half2_rn(r2, r3);
                }
            }
        }
        __syncthreads();

        // stage 2: e = conv(rb, kf); lat *= e; esum over interior.
        // rbt local col of ext x is x-1: output ext col j needs local
        // j-2..j+1 => q0 = (j-2,j-1), q1 = (j,j+1).   (verbatim R11)
        float esum = 0.f;
        #pragma unroll
        for (int up = 0; up < S2S; ++up) {
            if (2 * s <= s2mrg[up]) {
                const int ro = s2rb[up];
                const int lo = s2lat[up];
                const int mk = s2msk[up];
                #pragma unroll
                for (int c = 0; c < 3; ++c) {
                    float e0 = 0.f, e1 = 0.f;
                    #pragma unroll
                    for (int dy = 0; dy < 3; ++dy) {
                        const __half2* Rr = (const __half2*)
                            &rbt[c * RPS + ro + dy * RRS];
                        const float2 q0 = __half22float2(Rr[0]);
                        const float2 q1 = __half22float2(Rr[1]);
                        const float w0 = gkf[(dy * 3 + 0) * 3 + c];
                        const float w1 = gkf[(dy * 3 + 1) * 3 + c];
                        const float w2 = gkf[(dy * 3 + 2) * 3 + c];
                        e0 = fmaf(q0.x, w0, fmaf(q0.y, w1, fmaf(q1.x, w2, e0)));
                        e1 = fmaf(q0.y, w0, fmaf(q1.x, w1, fmaf(q1.y, w2, e1)));
                    }
                    float2* Lp = (float2*)&lat[c * LPS + lo];
                    float2 lv = *Lp;
                    lv.x *= e0; lv.y *= e1;
                    *Lp = lv;
                    esum += (mk & 1) ? e0 : 0.f;
                    esum += (mk & 2) ? e1 : 0.f;
                }
            }
        }
        if (wr_part) {
            #pragma unroll
            for (int off = 32; off; off >>= 1) esum += __shfl_down(esum, off, 64);
            if (lane == 0) wred[wid] = esum;
        }
        __syncthreads();     // lat writes done AND wred ready
        if (wr_part && tid == 0) {
            float t = 0.f;
            #pragma unroll
            for (int w2 = 0; w2 < NWAVES; ++w2) t += wred[w2];
            part[(base + s) * NBLKS + b] = t;
        }
    }

    // ---- write interior [8,40)^2 to dst ----
    for (int p = tid; p < 1024; p += BLK) {
        const int i = p >> 5, j = p & 31;
        const int l = (i + HALO) * LRS + (j + HALO);
        float* op = dst + nbase + ((size_t)(ty0 + i) * W + (tx0 + j)) * 3;
        op[0] = lat[l];
        op[1] = lat[LPS + l];
        op[2] = lat[2 * LPS + l];
    }
}

extern "C" void kernel_launch(void* const* d_in, const int* in_sizes, int n_in,
                              void* d_out, int out_size, void* d_ws, size_t ws_size,
                              hipStream_t stream) {
    const float* inputs = (const float*)d_in[0];
    const float* gk     = (const float*)d_in[1];
    const float* gkf    = (const float*)d_in[2];
    float* out = (float*)d_out;

    // ws: [0 .. 128KB) iteration partials [30][1024] | buffer A | buffer B
    char* ws = (char*)d_ws;
    float* part = (float*)ws;
    float* A    = (float*)(ws + 131072);
    float* Bb   = (float*)(ws + 131072 + (size_t)TOTAL * sizeof(float));

    // period-3 schedule; X[g] = latent at start of group g. X[8] = out.
    const float* X[9] = { inputs, A, out, Bb, A, out, Bb, A, out };

    for (int g = 0; g < 9; ++g) {
        const float* s  = X[(g == 8) ? 7 : g];
        const float* sp = X[(g == 0) ? 0 : g - 1];
        float*       d  = (float*)((g == 8) ? X[8] : X[g + 1]);
        rl_group<<<NBLKS, BLK, 0, stream>>>(inputs, gk, gkf, s, sp, d, part, g);
    }
}